// Round 14
// baseline (565.959 us; speedup 1.0000x reference)
//
#include <hip/hip_runtime.h>
#include <math.h>

#define DEVI __device__ __forceinline__

constexpr int CAMS = 6;
constexpr int CH   = 256;
constexpr int LTOT = 12096;   // 9216 + 2304 + 576
constexpr int TPC2 = 95;      // 128-row tiles per camera (last tile 64 valid rows)
constexpr int LIMG = 11520;   // 9216 + 2304

// ---------------- workspace layout (float units) ----------------
constexpr size_t WS_OM = 0;                               // M / out_mem [6][12096][256] (in-place)
constexpr size_t WS_SC = WS_OM + (size_t)CAMS*LTOT*CH;    // scores  [6][12096]
constexpr size_t WS_TI = WS_SC + (size_t)CAMS*LTOT;       // topk_ind  600 (int32)
constexpr size_t WS_TS = WS_TI + 768;                     // topk_scores 600
constexpr size_t WS_DA = WS_TS + 768;                     // dyn_all [600][64][4]
constexpr size_t WS_GI = WS_DA + (size_t)600*256;         // gidx 200 (int32)
constexpr size_t WS_GS = WS_GI + 256;                     // (spare)
constexpr size_t WS_GA = WS_GS + 256;                     // gamma [6][256]
constexpr size_t WS_BE = WS_GA + 1536;                    // beta  [6][256]
constexpr size_t WS_AI = WS_BE + 1536;                    // phaseA idx [36][100] int
constexpr size_t WS_AS = WS_AI + 3712;                    // phaseA scores [36][100]

// ---------------- output layout (float units) ----------------
constexpr size_t O_FF  = 0;                               // feat_flatten [6][11520][256]
constexpr size_t O_SP  = (size_t)CAMS*LIMG*CH;            // spatial [2][2]
constexpr size_t O_L2I = O_SP + 4;                        // lidar2img [1][6][4][4]
constexpr size_t O_DQ  = O_L2I + 96;                      // dyn_query [1][200][64][4]
constexpr size_t O_QF  = O_DQ + (size_t)200*64*4;         // qf_out [1][200][256]

DEVI float anchor_comp(int l, int j) {
    int W, wsh, ll; float Wf, Hf;
    if (l < 9216)      { W=128; wsh=7; Wf=128.f; Hf=72.f; ll=l; }
    else if (l < 11520){ W=64;  wsh=6; Wf=64.f;  Hf=36.f; ll=l-9216; }
    else               { W=32;  wsh=5; Wf=32.f;  Hf=18.f; ll=l-11520; }
    int y = ll >> wsh, x = ll & (W-1);
    float px = (x + 0.5f) / Wf;
    float py = (y + 0.5f) / Hf;
    bool valid = (px > 0.01f) && (px < 0.99f) && (py > 0.01f) && (py < 0.99f);
    if (!valid) return INFINITY;
    float p = (j == 0) ? px : py;
    return logf(p / (1.f - p));
}

// =====================================================================
// K1a: k_proj — M = mask * (feat^T @ w_proj)
// 128-row tiles, 256 threads = 8 rowgroups(16 rows) x 32 colgroups(8 cols),
// 16x8 micro-tile: per c-iter 6 b128 LDS reads per 128 FMA (25% less
// LDS-pipe traffic than 8x8 — R7-R12 showed the per-CU LDS pipe is the
// binding resource at 53% VALUBusy). W split-half layout (R9-verified
// 0 conflicts); A [8c][128tok] lane-linear; A reads 2-address broadcast.
// launch_bounds(256,1): acc[16][8]=128 VGPR + temps must not be capped
// at 128 (R4-R6 spill lesson). unroll 1 bounds in-flight LDS temps.
// =====================================================================
__global__ __launch_bounds__(256, 1)
void k_proj(const float* __restrict__ f0, const float* __restrict__ f1, const float* __restrict__ f2,
            const float* __restrict__ wp0, const float* __restrict__ wp1, const float* __restrict__ wp2,
            float* __restrict__ Mout)
{
    __shared__ __align__(16) float lds[2*2048 + 2*1024];   // 24 KB
    float* wbufs = lds;            // 2 x [8c][256] split-half layout
    float* abufs = lds + 4096;     // 2 x [8c][128tok]

    const int bx = blockIdx.x;
    const int n  = bx / TPC2;
    const int l0 = (bx % TPC2) * 128;
    const float* feat; const float* wp;
    int HW, lloc, W, wsh; float Wf, Hf;
    if (l0 < 9216)      { feat=f0; wp=wp0; HW=9216; lloc=l0;       W=128; wsh=7; Wf=128.f; Hf=72.f; }
    else if (l0 < 11520){ feat=f1; wp=wp1; HW=2304; lloc=l0-9216;  W=64;  wsh=6; Wf=64.f;  Hf=36.f; }
    else                { feat=f2; wp=wp2; HW=576;  lloc=l0-11520; W=32;  wsh=5; Wf=32.f;  Hf=18.f; }
    const float* featn = feat + (size_t)n*CH*HW;

    const int tid = threadIdx.x;
    const int rg  = tid >> 5;          // rowgroup 0..7 (rows rg*16..+15)
    const int cg  = tid & 31;          // colgroup 0..31 (cols cg*8..+7)
    const int sc_ = tid >> 5;          // W staging c-row 0..7
    const int sg  = tid & 31;          // W staging granule (8 floats)
    const int ac  = tid >> 5;          // A staging channel 0..7
    const int at4 = (tid & 31) * 4;    // A staging token*4 (0..124)

    float4 wreg0, wreg1, areg;

    auto loadW = [&](int ck) {
        const float* p = wp + (size_t)(ck*8 + sc_)*256 + sg*8;
        wreg0 = *reinterpret_cast<const float4*>(p);
        wreg1 = *reinterpret_cast<const float4*>(p + 4);
    };
    auto writeW = [&](int b) {
        float* d = wbufs + b*2048 + sc_*256;
        *reinterpret_cast<float4*>(d + sg*4)       = wreg0;   // cols sg*8..+3
        *reinterpret_cast<float4*>(d + 128 + sg*4) = wreg1;   // cols sg*8+4..+7
    };
    auto loadA = [&](int ck) {
        int off = lloc + at4;
        if (off > HW - 4) off = HW - 4;   // clamp (last tile of level 2)
        areg = *reinterpret_cast<const float4*>(featn + (size_t)(ck*8 + ac)*HW + off);
    };
    auto writeA = [&](int b) {
        *reinterpret_cast<float4*>(abufs + b*1024 + tid*4) = areg;   // slot ac*128+at4
    };

    float acc[16][8];
    #pragma unroll
    for (int r=0;r<16;++r)
        #pragma unroll
        for (int j=0;j<8;++j) acc[r][j] = 0.f;

    loadW(0); loadA(0);
    writeW(0); writeA(0);
    __syncthreads();
    int buf = 0;
    for (int k = 0; k < 32; ++k) {
        if (k < 31) { loadW(k+1); loadA(k+1); }
        const float* wb = wbufs + buf*2048;
        const float* ab = abufs + buf*1024;
        #pragma unroll 1
        for (int c = 0; c < 8; ++c) {
            float4 a0 = *reinterpret_cast<const float4*>(ab + c*128 + rg*16);
            float4 a1 = *reinterpret_cast<const float4*>(ab + c*128 + rg*16 + 4);
            float4 a2 = *reinterpret_cast<const float4*>(ab + c*128 + rg*16 + 8);
            float4 a3 = *reinterpret_cast<const float4*>(ab + c*128 + rg*16 + 12);
            float4 w0 = *reinterpret_cast<const float4*>(wb + c*256 + cg*4);
            float4 w1 = *reinterpret_cast<const float4*>(wb + c*256 + 128 + cg*4);
            float av[16] = {a0.x,a0.y,a0.z,a0.w, a1.x,a1.y,a1.z,a1.w,
                            a2.x,a2.y,a2.z,a2.w, a3.x,a3.y,a3.z,a3.w};
            float wv[8]  = {w0.x,w0.y,w0.z,w0.w, w1.x,w1.y,w1.z,w1.w};
            #pragma unroll
            for (int r=0;r<16;++r)
                #pragma unroll
                for (int j=0;j<8;++j)
                    acc[r][j] = fmaf(av[r], wv[j], acc[r][j]);
        }
        if (k < 31) { writeW(buf^1); writeA(buf^1); }
        __syncthreads();
        buf ^= 1;
    }

    // mask + write M (guard: last tile of level 2 has only 64 valid rows)
    #pragma unroll
    for (int r=0;r<16;++r) {
        int glob = l0 + rg*16 + r;
        if (glob >= LTOT) continue;
        int ll = lloc + rg*16 + r;
        int y = ll >> wsh, x = ll & (W-1);
        float px = (x + 0.5f) / Wf;
        float py = (y + 0.5f) / Hf;
        bool valid = (px > 0.01f) && (px < 0.99f) && (py > 0.01f) && (py < 0.99f);
        float m = valid ? 1.f : 0.f;
        float* dst = Mout + ((size_t)n*LTOT + glob)*CH + cg*8;
        *reinterpret_cast<float4*>(dst)   = make_float4(acc[r][0]*m,acc[r][1]*m,acc[r][2]*m,acc[r][3]*m);
        *reinterpret_cast<float4*>(dst+4) = make_float4(acc[r][4]*m,acc[r][5]*m,acc[r][6]*m,acc[r][7]*m);
    }
}

// =====================================================================
// K1b: k_enc — out = LN(M @ w_enc + b_enc), scores = max_cls(out@w_cls+b)
// Same 16x8 structure; A chunks transposed from M (scalar stride-128
// writes, 2-way/free). In-place M overwrite (tile rows block-private).
// =====================================================================
__global__ __launch_bounds__(256, 1)
void k_enc(float* __restrict__ M,
           const float* __restrict__ w_enc, const float* __restrict__ b_enc,
           const float* __restrict__ ln_g, const float* __restrict__ ln_b,
           const float* __restrict__ w_cls, const float* __restrict__ b_cls,
           float* __restrict__ scores)
{
    __shared__ __align__(16) float lds[2*2048 + 2*1024];   // 24 KB
    float* wbufs = lds;
    float* abufs = lds + 4096;

    const int bx = blockIdx.x;
    const int n  = bx / TPC2;
    const int l0 = (bx % TPC2) * 128;

    const int tid = threadIdx.x;
    const int rg  = tid >> 5;          // rowgroup 0..7 (rows rg*16..+15)
    const int cg  = tid & 31;          // colgroup 0..31
    const int sc_ = tid >> 5;
    const int sg  = tid & 31;
    const int tok = tid & 127;         // A staging: token 0..127
    const int cp  = (tid >> 7) * 4;    // A staging: channel quad 0 or 4

    float4 wreg0, wreg1, mreg;

    auto loadW = [&](int ck) {
        const float* p = w_enc + (size_t)(ck*8 + sc_)*256 + sg*8;
        wreg0 = *reinterpret_cast<const float4*>(p);
        wreg1 = *reinterpret_cast<const float4*>(p + 4);
    };
    auto writeW = [&](int b) {
        float* d = wbufs + b*2048 + sc_*256;
        *reinterpret_cast<float4*>(d + sg*4)       = wreg0;
        *reinterpret_cast<float4*>(d + 128 + sg*4) = wreg1;
    };
    auto loadA = [&](int ck) {
        // rows beyond LTOT read into the scores region of ws: defined garbage,
        // propagates only into discarded (guarded) output rows.
        mreg = *reinterpret_cast<const float4*>(M + ((size_t)n*LTOT + l0 + tok)*CH + ck*8 + cp);
    };
    auto writeA = [&](int b) {
        float* d = abufs + b*1024 + tok;
        d[(cp+0)*128] = mreg.x;
        d[(cp+1)*128] = mreg.y;
        d[(cp+2)*128] = mreg.z;
        d[(cp+3)*128] = mreg.w;
    };

    float acc[16][8];
    #pragma unroll
    for (int r=0;r<16;++r)
        #pragma unroll
        for (int j=0;j<8;++j) acc[r][j] = 0.f;

    loadW(0); loadA(0);
    writeW(0); writeA(0);
    __syncthreads();
    int buf = 0;
    for (int k = 0; k < 32; ++k) {
        if (k < 31) { loadW(k+1); loadA(k+1); }
        const float* wb = wbufs + buf*2048;
        const float* ab = abufs + buf*1024;
        #pragma unroll 1
        for (int c = 0; c < 8; ++c) {
            float4 a0 = *reinterpret_cast<const float4*>(ab + c*128 + rg*16);
            float4 a1 = *reinterpret_cast<const float4*>(ab + c*128 + rg*16 + 4);
            float4 a2 = *reinterpret_cast<const float4*>(ab + c*128 + rg*16 + 8);
            float4 a3 = *reinterpret_cast<const float4*>(ab + c*128 + rg*16 + 12);
            float4 w0 = *reinterpret_cast<const float4*>(wb + c*256 + cg*4);
            float4 w1 = *reinterpret_cast<const float4*>(wb + c*256 + 128 + cg*4);
            float av[16] = {a0.x,a0.y,a0.z,a0.w, a1.x,a1.y,a1.z,a1.w,
                            a2.x,a2.y,a2.z,a2.w, a3.x,a3.y,a3.z,a3.w};
            float wv[8]  = {w0.x,w0.y,w0.z,w0.w, w1.x,w1.y,w1.z,w1.w};
            #pragma unroll
            for (int r=0;r<16;++r)
                #pragma unroll
                for (int j=0;j<8;++j)
                    acc[r][j] = fmaf(av[r], wv[j], acc[r][j]);
        }
        if (k < 31) { writeW(buf^1); writeA(buf^1); }
        __syncthreads();
        buf ^= 1;
    }

    // + b_enc, LayerNorm (row reduce across the 32 cg lanes)
    {
        float4 be0 = *reinterpret_cast<const float4*>(b_enc + cg*8);
        float4 be1 = *reinterpret_cast<const float4*>(b_enc + cg*8 + 4);
        float4 g0  = *reinterpret_cast<const float4*>(ln_g  + cg*8);
        float4 g1  = *reinterpret_cast<const float4*>(ln_g  + cg*8 + 4);
        float4 bb0 = *reinterpret_cast<const float4*>(ln_b  + cg*8);
        float4 bb1 = *reinterpret_cast<const float4*>(ln_b  + cg*8 + 4);
        float bev[8] = {be0.x,be0.y,be0.z,be0.w, be1.x,be1.y,be1.z,be1.w};
        float gv[8]  = {g0.x,g0.y,g0.z,g0.w, g1.x,g1.y,g1.z,g1.w};
        float bv[8]  = {bb0.x,bb0.y,bb0.z,bb0.w, bb1.x,bb1.y,bb1.z,bb1.w};
        #pragma unroll
        for (int r=0;r<16;++r) {
            float s = 0.f;
            #pragma unroll
            for (int j=0;j<8;++j) { acc[r][j] += bev[j]; s += acc[r][j]; }
            s += __shfl_xor(s,1); s += __shfl_xor(s,2); s += __shfl_xor(s,4);
            s += __shfl_xor(s,8); s += __shfl_xor(s,16);
            float mean = s * (1.f/256.f);
            float vs = 0.f;
            #pragma unroll
            for (int j=0;j<8;++j) { float d = acc[r][j]-mean; vs = fmaf(d,d,vs); }
            vs += __shfl_xor(vs,1); vs += __shfl_xor(vs,2); vs += __shfl_xor(vs,4);
            vs += __shfl_xor(vs,8); vs += __shfl_xor(vs,16);
            float rs = 1.f / sqrtf(vs*(1.f/256.f) + 1e-5f);
            #pragma unroll
            for (int j=0;j<8;++j) acc[r][j] = (acc[r][j]-mean)*rs*gv[j] + bv[j];
        }
    }

    // write out_mem in place + scores (guarded)
    {
        float bcl[10];
        #pragma unroll
        for (int c=0;c<10;++c) bcl[c] = b_cls[c];
        #pragma unroll
        for (int r=0;r<16;++r) {
            int glob = l0 + rg*16 + r;
            if (glob < LTOT) {
                float* dst = M + ((size_t)n*LTOT + glob)*CH + cg*8;
                *reinterpret_cast<float4*>(dst)   = make_float4(acc[r][0],acc[r][1],acc[r][2],acc[r][3]);
                *reinterpret_cast<float4*>(dst+4) = make_float4(acc[r][4],acc[r][5],acc[r][6],acc[r][7]);
            }
            float p[10];
            #pragma unroll
            for (int c=0;c<10;++c) p[c] = 0.f;
            #pragma unroll
            for (int i=0;i<8;++i) {
                const float* wc = w_cls + (cg*8+i)*10;
                float a = acc[r][i];
                #pragma unroll
                for (int c=0;c<10;c+=2) {
                    float2 w2 = *reinterpret_cast<const float2*>(wc + c);
                    p[c]   = fmaf(a, w2.x, p[c]);
                    p[c+1] = fmaf(a, w2.y, p[c+1]);
                }
            }
            #pragma unroll
            for (int c=0;c<10;++c) {
                p[c] += __shfl_xor(p[c],1); p[c] += __shfl_xor(p[c],2);
                p[c] += __shfl_xor(p[c],4); p[c] += __shfl_xor(p[c],8);
                p[c] += __shfl_xor(p[c],16);
            }
            if (cg == 0 && glob < LTOT) {
                float mx = -INFINITY;
                #pragma unroll
                for (int c=0;c<10;++c) mx = fmaxf(mx, p[c] + bcl[c]);
                scores[(size_t)n*LTOT + glob] = mx;
            }
        }
    }
}

// =====================================================================
// sort-based top-k (exact lax.top_k semantics)
// =====================================================================
typedef unsigned long long u64;

DEVI u64 pack_key(float s, unsigned idx) {
    unsigned u = __float_as_uint(s);
    u = (u & 0x80000000u) ? ~u : (u | 0x80000000u);
    return ((u64)u << 32) | (unsigned)(~idx);
}
DEVI float key_score(u64 k) {
    unsigned u = (unsigned)(k >> 32);
    u = (u & 0x80000000u) ? (u ^ 0x80000000u) : ~u;
    return __uint_as_float(u);
}
DEVI int key_idx(u64 k) { return (int)(~(unsigned)k); }

template<int N>
DEVI void bitonic_desc(u64* s, int tid) {
    for (int size = 2; size <= N; size <<= 1) {
        for (int stride = size >> 1; stride > 0; stride >>= 1) {
            __syncthreads();
            #pragma unroll 2
            for (int t = tid; t < N/2; t += 256) {
                int lo = ((t & ~(stride-1)) << 1) | (t & (stride-1));
                int hi = lo + stride;
                bool desc = ((lo & size) == 0);
                u64 a = s[lo], b = s[hi];
                if ((a < b) == desc) { s[lo] = b; s[hi] = a; }
            }
        }
    }
    __syncthreads();
}

__global__ __launch_bounds__(256)
void k_sortA(const float* __restrict__ scores, int* __restrict__ outi, float* __restrict__ outs)
{
    __shared__ u64 s[2048];
    const int b = blockIdx.x, tid = threadIdx.x;
    const int cam = b / 6, seg = b % 6;
    const float* v = scores + (size_t)cam*LTOT + seg*2016;
    for (int i = tid; i < 2048; i += 256)
        s[i] = (i < 2016) ? pack_key(v[i], seg*2016 + i) : 0ull;
    bitonic_desc<2048>(s, tid);
    if (tid < 100) {
        u64 k = s[tid];
        outi[b*100 + tid] = key_idx(k);
        outs[b*100 + tid] = key_score(k);
    }
}

__global__ __launch_bounds__(256)
void k_sortB(const int* __restrict__ ai, const float* __restrict__ as,
             int* __restrict__ ti, float* __restrict__ ts)
{
    __shared__ u64 s[1024];
    const int cam = blockIdx.x, tid = threadIdx.x;
    for (int i = tid; i < 1024; i += 256)
        s[i] = (i < 600) ? pack_key(as[cam*600 + i], (unsigned)ai[cam*600 + i]) : 0ull;
    bitonic_desc<1024>(s, tid);
    if (tid < 100) {
        u64 k = s[tid];
        ti[cam*100 + tid] = key_idx(k);
        ts[cam*100 + tid] = key_score(k);
    }
}

__global__ __launch_bounds__(256)
void k_sortC(const float* __restrict__ ts, int* __restrict__ gi)
{
    __shared__ u64 s[1024];
    const int tid = threadIdx.x;
    for (int i = tid; i < 1024; i += 256)
        s[i] = (i < 600) ? pack_key(ts[i], (unsigned)i) : 0ull;
    bitonic_desc<1024>(s, tid);
    if (tid < 200) gi[tid] = key_idx(s[tid]);
}

// =====================================================================
// K3: per selected query: bbox MLP + depth net + center2lidar
// =====================================================================
__global__ __launch_bounds__(256)
void k_query(const float* __restrict__ out_mem, const int* __restrict__ topk_ind,
             const float* __restrict__ intr, const float* __restrict__ ext_inv,
             const float* __restrict__ w_bb1, const float* __restrict__ b_bb1,
             const float* __restrict__ w_bb2, const float* __restrict__ b_bb2,
             const float* __restrict__ w_bb3, const float* __restrict__ b_bb3,
             const float* __restrict__ depth_bins,
             const float* __restrict__ w_d1, const float* __restrict__ b_d1,
             const float* __restrict__ w_d2, const float* __restrict__ b_d2,
             float* __restrict__ dyn_all)
{
    __shared__ float sq[272];
    __shared__ float sh[256];
    __shared__ float sh2[256];
    __shared__ float sbb[2];
    const int nk = blockIdx.x;
    const int n = nk / 100;
    const int tid = threadIdx.x;
    const int l = topk_ind[nk];
    sq[tid] = out_mem[((size_t)n*LTOT + l)*CH + tid];
    if (tid < 16) sq[256+tid] = intr[n*16+tid] * 0.01f;
    __syncthreads();
    float s1 = b_bb1[tid];
    for (int c=0;c<256;++c) s1 = fmaf(sq[c], w_bb1[c*256+tid], s1);
    sh[tid] = fmaxf(s1, 0.f);
    __syncthreads();
    float s2 = b_bb2[tid];
    for (int c=0;c<256;++c) s2 = fmaf(sh[c], w_bb2[c*256+tid], s2);
    sh2[tid] = fmaxf(s2, 0.f);
    __syncthreads();
    {
        int j = tid >> 6, c0 = tid & 63;
        if (j < 2) {
            float p = 0.f;
            #pragma unroll
            for (int t=0;t<4;++t) { int c = c0 + t*64; p = fmaf(sh2[c], w_bb3[c*4+j], p); }
            #pragma unroll
            for (int m=1;m<64;m<<=1) p += __shfl_xor(p, m);
            if (c0 == 0) sbb[j] = p + b_bb3[j] + anchor_comp(l, j);
        }
    }
    float t1 = b_d1[tid];
    for (int c=0;c<272;++c) t1 = fmaf(sq[c], w_d1[c*256+tid], t1);
    sh[tid] = fmaxf(t1, 0.f);
    __syncthreads();
    if (tid < 64) {
        float dl = b_d2[tid];
        for (int c=0;c<256;++c) dl = fmaf(sh[c], w_d2[c*64+tid], dl);
        if (isnan(dl)) dl = 0.f;
        if (isinf(dl)) dl = (dl > 0.f) ? 1e4f : -1e4f;
        float mx = dl;
        #pragma unroll
        for (int m=1;m<64;m<<=1) mx = fmaxf(mx, __shfl_xor(mx, m));
        float e = expf(dl - mx);
        float sum = e;
        #pragma unroll
        for (int m=1;m<64;m<<=1) sum += __shfl_xor(sum, m);
        float dp = e / sum;
        float fx = fmaxf(intr[n*16+0], 1e-6f);
        float fy = fmaxf(intr[n*16+5], 1e-6f);
        float cx = intr[n*16+2], cy = intr[n*16+6];
        float sx = 1.f/(1.f+expf(-sbb[0]));
        float sy = 1.f/(1.f+expf(-sbb[1]));
        float c2dx = sx * 1024.f, c2dy = sy * 576.f;
        float dep = depth_bins[tid];
        float X = (c2dx - cx)/fx*dep;
        float Y = (c2dy - cy)/fy*dep;
        const float* EI = ext_inv + n*16;
        float c0v = EI[0]*X + EI[1]*Y + EI[2]*dep + EI[3];
        float c1v = EI[4]*X + EI[5]*Y + EI[6]*dep + EI[7];
        float c2v = EI[8]*X + EI[9]*Y + EI[10]*dep + EI[11];
        float4 o = make_float4(c0v, c1v, c2v, dp);
        *reinterpret_cast<float4*>(dyn_all + ((size_t)nk*64 + tid)*4) = o;
    }
}

// =====================================================================
// K5: gather final 200 queries
// =====================================================================
__global__ __launch_bounds__(256)
void k_gather(const float* __restrict__ dyn_all, const int* __restrict__ gidx,
              const int* __restrict__ topk_ind, const float* __restrict__ out_mem,
              float* __restrict__ out)
{
    int g = blockIdx.x, tid = threadIdx.x;
    int src = gidx[g];
    out[O_DQ + (size_t)g*256 + tid] = dyn_all[(size_t)src*256 + tid];
    int n = src/100; int l = topk_ind[src];
    out[O_QF + (size_t)g*256 + tid] = out_mem[((size_t)n*LTOT + l)*CH + tid];
}

// =====================================================================
// K6a: MLN gamma/beta per camera
// =====================================================================
__global__ __launch_bounds__(256)
void k_mln(const float* __restrict__ intr, const float* __restrict__ ext,
           const float* __restrict__ w_m1, const float* __restrict__ b_m1,
           const float* __restrict__ w_mg, const float* __restrict__ b_mg,
           const float* __restrict__ w_mb, const float* __restrict__ b_mb,
           float* __restrict__ gamma, float* __restrict__ beta)
{
    __shared__ float hm[256];
    int tid = threadIdx.x;
    for (int n=0;n<CAMS;++n) {
        float m[14];
        m[0] = intr[n*16+0] / 1000.0f;
        m[1] = intr[n*16+5] / 1000.0f;
        #pragma unroll
        for (int j=0;j<12;++j) m[2+j] = ext[n*16+j];
        float h = b_m1[tid];
        #pragma unroll
        for (int k=0;k<14;++k) h = fmaf(m[k], w_m1[k*256+tid], h);
        hm[tid] = fmaxf(h, 0.f);
        __syncthreads();
        float g = b_mg[tid], bt = b_mb[tid];
        for (int c=0;c<256;++c) {
            float hv = hm[c];
            g  = fmaf(hv, w_mg[c*256+tid], g);
            bt = fmaf(hv, w_mb[c*256+tid], bt);
        }
        gamma[n*256+tid] = g;
        beta[n*256+tid]  = bt;
        __syncthreads();
    }
}

// =====================================================================
// K6b: feat_flatten = transpose(feat) * gamma + beta  (64x64 LDS tiles)
// =====================================================================
__global__ __launch_bounds__(256)
void k_flatten(const float* __restrict__ f0, const float* __restrict__ f1,
               const float* __restrict__ gamma, const float* __restrict__ beta,
               float* __restrict__ out)
{
    __shared__ float t[64][65];
    int b = blockIdx.x;
    int lt = b % 180, ct = (b/180) & 3, n = b / 720;
    int l0 = lt*64, c0 = ct*64;
    const float* f; int HW, lb;
    if (l0 < 9216) { f=f0; HW=9216; lb=l0; } else { f=f1; HW=2304; lb=l0-9216; }
    int tid = threadIdx.x;
    int cl = tid >> 4, lw = (tid & 15)*4;
    #pragma unroll
    for (int rep=0;rep<4;++rep) {
        int cc = cl + rep*16;
        float4 v = *reinterpret_cast<const float4*>(f + ((size_t)n*CH + c0+cc)*HW + lb + lw);
        t[cc][lw+0]=v.x; t[cc][lw+1]=v.y; t[cc][lw+2]=v.z; t[cc][lw+3]=v.w;
    }
    __syncthreads();
    int ll = tid >> 4, cw = (tid & 15)*4;
    float4 gv = *reinterpret_cast<const float4*>(gamma + n*256 + c0 + cw);
    float4 bv = *reinterpret_cast<const float4*>(beta  + n*256 + c0 + cw);
    #pragma unroll
    for (int rep=0;rep<4;++rep) {
        int l = ll + rep*16;
        float4 o;
        o.x = fmaf(t[cw+0][l], gv.x, bv.x);
        o.y = fmaf(t[cw+1][l], gv.y, bv.y);
        o.z = fmaf(t[cw+2][l], gv.z, bv.z);
        o.w = fmaf(t[cw+3][l], gv.w, bv.w);
        *reinterpret_cast<float4*>(out + ((size_t)n*LIMG + l0 + l)*CH + c0 + cw) = o;
    }
}

// =====================================================================
// K7: spatial_flatten consts + lidar2img
// =====================================================================
__global__ void k_small(const float* __restrict__ intr, const float* __restrict__ ext,
                        float* __restrict__ out)
{
    int tid = threadIdx.x;
    if (tid < 4) {
        const float sp[4] = {72.f, 128.f, 36.f, 64.f};
        out[O_SP + tid] = sp[tid];
    }
    if (tid < 96) {
        int n = tid >> 4, i = (tid >> 2) & 3, k = tid & 3;
        float s = 0.f;
        #pragma unroll
        for (int j=0;j<4;++j) s = fmaf(intr[n*16 + i*4 + j], ext[n*16 + j*4 + k], s);
        out[O_L2I + tid] = s;
    }
}

// =====================================================================
extern "C" void kernel_launch(void* const* d_in, const int* in_sizes, int n_in,
                              void* d_out, int out_size, void* d_ws, size_t ws_size,
                              hipStream_t stream) {
    const float* f0      = (const float*)d_in[0];
    const float* f1      = (const float*)d_in[1];
    const float* f2      = (const float*)d_in[2];
    const float* intr    = (const float*)d_in[3];
    const float* ext     = (const float*)d_in[4];
    const float* ext_inv = (const float*)d_in[5];
    const float* wp0     = (const float*)d_in[6];
    const float* wp1     = (const float*)d_in[7];
    const float* wp2     = (const float*)d_in[8];
    const float* w_enc   = (const float*)d_in[9];
    const float* b_enc   = (const float*)d_in[10];
    const float* ln_g    = (const float*)d_in[11];
    const float* ln_b    = (const float*)d_in[12];
    const float* w_cls   = (const float*)d_in[13];
    const float* b_cls   = (const float*)d_in[14];
    const float* w_bb1   = (const float*)d_in[15];
    const float* b_bb1   = (const float*)d_in[16];
    const float* w_bb2   = (const float*)d_in[17];
    const float* b_bb2   = (const float*)d_in[18];
    const float* w_bb3   = (const float*)d_in[19];
    const float* b_bb3   = (const float*)d_in[20];
    const float* dbins   = (const float*)d_in[21];
    const float* w_d1    = (const float*)d_in[22];
    const float* b_d1    = (const float*)d_in[23];
    const float* w_d2    = (const float*)d_in[24];
    const float* b_d2    = (const float*)d_in[25];
    const float* w_m1    = (const float*)d_in[26];
    const float* b_m1    = (const float*)d_in[27];
    const float* w_mg    = (const float*)d_in[28];
    const float* b_mg    = (const float*)d_in[29];
    const float* w_mb    = (const float*)d_in[30];
    const float* b_mb    = (const float*)d_in[31];

    float* ws  = (float*)d_ws;
    float* out = (float*)d_out;
    float* om  = ws + WS_OM;
    float* sc  = ws + WS_SC;
    int*   ti  = (int*)(ws + WS_TI);
    float* ts  = ws + WS_TS;
    float* da  = ws + WS_DA;
    int*   gi  = (int*)(ws + WS_GI);
    float* ga  = ws + WS_GA;
    float* be  = ws + WS_BE;
    int*   ai  = (int*)(ws + WS_AI);
    float* as  = ws + WS_AS;

    k_proj<<<CAMS*TPC2, 256, 0, stream>>>(f0, f1, f2, wp0, wp1, wp2, om);
    k_enc<<<CAMS*TPC2, 256, 0, stream>>>(om, w_enc, b_enc, ln_g, ln_b, w_cls, b_cls, sc);
    k_sortA<<<36, 256, 0, stream>>>(sc, ai, as);
    k_sortB<<<6, 256, 0, stream>>>(ai, as, ti, ts);
    k_query<<<600, 256, 0, stream>>>(om, ti, intr, ext_inv,
                                     w_bb1, b_bb1, w_bb2, b_bb2, w_bb3, b_bb3,
                                     dbins, w_d1, b_d1, w_d2, b_d2, da);
    k_sortC<<<1, 256, 0, stream>>>(ts, gi);
    k_gather<<<200, 256, 0, stream>>>(da, gi, ti, om, out);
    k_mln<<<1, 256, 0, stream>>>(intr, ext, w_m1, b_m1, w_mg, b_mg, w_mb, b_mb, ga, be);
    k_flatten<<<6*4*180, 256, 0, stream>>>(f0, f1, ga, be, out);
    k_small<<<1, 128, 0, stream>>>(intr, ext, out);
}

// Round 15
// 420.818 us; speedup vs baseline: 1.3449x; 1.3449x over previous
//
#include <hip/hip_runtime.h>
#include <math.h>

#define DEVI __device__ __forceinline__

constexpr int CAMS = 6;
constexpr int CH   = 256;
constexpr int LTOT = 12096;   // 9216 + 2304 + 576
constexpr int TPC  = 189;     // 64-row tiles per camera
constexpr int LIMG = 11520;   // 9216 + 2304

// ---------------- workspace layout (float units) ----------------
constexpr size_t WS_OM = 0;                               // M / out_mem [6][12096][256] (in-place)
constexpr size_t WS_SC = WS_OM + (size_t)CAMS*LTOT*CH;    // scores  [6][12096]
constexpr size_t WS_TI = WS_SC + (size_t)CAMS*LTOT;       // topk_ind  600 (int32)
constexpr size_t WS_TS = WS_TI + 768;                     // topk_scores 600
constexpr size_t WS_DA = WS_TS + 768;                     // dyn_all [600][64][4]
constexpr size_t WS_GI = WS_DA + (size_t)600*256;         // gidx 200 (int32)
constexpr size_t WS_GS = WS_GI + 256;                     // (spare)
constexpr size_t WS_GA = WS_GS + 256;                     // gamma [6][256]
constexpr size_t WS_BE = WS_GA + 1536;                    // beta  [6][256]
constexpr size_t WS_AI = WS_BE + 1536;                    // phaseA idx [36][100] int
constexpr size_t WS_AS = WS_AI + 3712;                    // phaseA scores [36][100]

// ---------------- output layout (float units) ----------------
constexpr size_t O_FF  = 0;                               // feat_flatten [6][11520][256]
constexpr size_t O_SP  = (size_t)CAMS*LIMG*CH;            // spatial [2][2]
constexpr size_t O_L2I = O_SP + 4;                        // lidar2img [1][6][4][4]
constexpr size_t O_DQ  = O_L2I + 96;                      // dyn_query [1][200][64][4]
constexpr size_t O_QF  = O_DQ + (size_t)200*64*4;         // qf_out [1][200][256]

DEVI float anchor_comp(int l, int j) {
    int W, wsh, ll; float Wf, Hf;
    if (l < 9216)      { W=128; wsh=7; Wf=128.f; Hf=72.f; ll=l; }
    else if (l < 11520){ W=64;  wsh=6; Wf=64.f;  Hf=36.f; ll=l-9216; }
    else               { W=32;  wsh=5; Wf=32.f;  Hf=18.f; ll=l-11520; }
    int y = ll >> wsh, x = ll & (W-1);
    float px = (x + 0.5f) / Wf;
    float py = (y + 0.5f) / Hf;
    bool valid = (px > 0.01f) && (px < 0.99f) && (py > 0.01f) && (py < 0.99f);
    if (!valid) return INFINITY;
    float p = (j == 0) ? px : py;
    return logf(p / (1.f - p));
}

// =====================================================================
// K1a: k_proj — M = mask * (feat^T @ w_proj)
// R12 config (best measured: 172us/kernel, 53% VALU, 0 conflicts, no
// spill). 64-row tiles, 256 thr = 8 rowgroups x 32 colgroups, 8x8
// micro-tile; W split-half LDS layout; unroll 2 (R6 spill lesson);
// launch_bounds(256,3) -> VGPR 68, no spill.
// =====================================================================
__global__ __launch_bounds__(256, 3)
void k_proj(const float* __restrict__ f0, const float* __restrict__ f1, const float* __restrict__ f2,
            const float* __restrict__ wp0, const float* __restrict__ wp1, const float* __restrict__ wp2,
            float* __restrict__ Mout)
{
    __shared__ __align__(16) float lds[2*2048 + 2*512];   // 20 KB
    float* wbufs = lds;            // 2 x [8c][256] split-half layout
    float* abufs = lds + 4096;     // 2 x [8c][64tok]

    const int bx = blockIdx.x;
    const int n  = bx / TPC;
    const int l0 = (bx % TPC) * 64;
    const float* feat; const float* wp;
    int HW, lloc, W, wsh; float Wf, Hf;
    if (l0 < 9216)      { feat=f0; wp=wp0; HW=9216; lloc=l0;       W=128; wsh=7; Wf=128.f; Hf=72.f; }
    else if (l0 < 11520){ feat=f1; wp=wp1; HW=2304; lloc=l0-9216;  W=64;  wsh=6; Wf=64.f;  Hf=36.f; }
    else                { feat=f2; wp=wp2; HW=576;  lloc=l0-11520; W=32;  wsh=5; Wf=32.f;  Hf=18.f; }
    const float* featn = feat + (size_t)n*CH*HW;

    const int tid  = threadIdx.x;
    const int rg   = tid >> 5;          // rowgroup 0..7
    const int cg   = tid & 31;          // colgroup 0..31
    const int sc_  = tid >> 5;          // staging c-row 0..7
    const int sg   = tid & 31;          // staging granule 0..31 (8 floats)
    const int arow = tid >> 4;          // A staging row 0..7 (tid<128)
    const int ag   = tid & 15;

    float4 wreg0, wreg1;
    float4 areg;

    auto loadW = [&](int ck) {
        const float* p = wp + (size_t)(ck*8 + sc_)*256 + sg*8;
        wreg0 = *reinterpret_cast<const float4*>(p);
        wreg1 = *reinterpret_cast<const float4*>(p + 4);
    };
    auto writeW = [&](int b) {
        float* d = wbufs + b*2048 + sc_*256;
        *reinterpret_cast<float4*>(d + sg*4)       = wreg0;   // cols sg*8..+3
        *reinterpret_cast<float4*>(d + 128 + sg*4) = wreg1;   // cols sg*8+4..+7
    };
    auto loadA = [&](int ck) {
        if (tid < 128)
            areg = *reinterpret_cast<const float4*>(featn + (size_t)(ck*8 + arow)*HW + lloc + ag*4);
    };
    auto writeA = [&](int b) {
        if (tid < 128)
            *reinterpret_cast<float4*>(abufs + b*512 + arow*64 + ag*4) = areg;
    };

    float acc[8][8];
    #pragma unroll
    for (int r=0;r<8;++r)
        #pragma unroll
        for (int j=0;j<8;++j) acc[r][j] = 0.f;

    loadW(0); loadA(0);
    writeW(0); writeA(0);
    __syncthreads();
    int buf = 0;
    for (int k = 0; k < 32; ++k) {
        if (k < 31) { loadW(k+1); loadA(k+1); }
        const float* wb = wbufs + buf*2048;
        const float* ab = abufs + buf*512;
        #pragma unroll 2
        for (int c = 0; c < 8; ++c) {
            float4 a0 = *reinterpret_cast<const float4*>(ab + c*64 + rg*8);
            float4 a1 = *reinterpret_cast<const float4*>(ab + c*64 + rg*8 + 4);
            float4 w0 = *reinterpret_cast<const float4*>(wb + c*256 + cg*4);
            float4 w1 = *reinterpret_cast<const float4*>(wb + c*256 + 128 + cg*4);
            float av[8] = {a0.x,a0.y,a0.z,a0.w, a1.x,a1.y,a1.z,a1.w};
            float wv[8] = {w0.x,w0.y,w0.z,w0.w, w1.x,w1.y,w1.z,w1.w};
            #pragma unroll
            for (int r=0;r<8;++r)
                #pragma unroll
                for (int j=0;j<8;++j)
                    acc[r][j] = fmaf(av[r], wv[j], acc[r][j]);
        }
        if (k < 31) { writeW(buf^1); writeA(buf^1); }
        __syncthreads();
        buf ^= 1;
    }

    // mask + write M
    #pragma unroll
    for (int r=0;r<8;++r) {
        int ll = lloc + rg*8 + r;
        int y = ll >> wsh, x = ll & (W-1);
        float px = (x + 0.5f) / Wf;
        float py = (y + 0.5f) / Hf;
        bool valid = (px > 0.01f) && (px < 0.99f) && (py > 0.01f) && (py < 0.99f);
        float m = valid ? 1.f : 0.f;
        float* dst = Mout + ((size_t)n*LTOT + l0 + rg*8 + r)*CH + cg*8;
        *reinterpret_cast<float4*>(dst)   = make_float4(acc[r][0]*m,acc[r][1]*m,acc[r][2]*m,acc[r][3]*m);
        *reinterpret_cast<float4*>(dst+4) = make_float4(acc[r][4]*m,acc[r][5]*m,acc[r][6]*m,acc[r][7]*m);
    }
}

// =====================================================================
// K1b: k_enc — out = LN(M @ w_enc + b_enc), scores = max_cls(out@w_cls+b)
// Reads its own 64-row tile of M, overwrites in place (block-private).
// =====================================================================
__global__ __launch_bounds__(256, 3)
void k_enc(float* __restrict__ M,
           const float* __restrict__ w_enc, const float* __restrict__ b_enc,
           const float* __restrict__ ln_g, const float* __restrict__ ln_b,
           const float* __restrict__ w_cls, const float* __restrict__ b_cls,
           float* __restrict__ scores)
{
    __shared__ __align__(16) float lds[2*2048 + 2*512];   // 20 KB
    float* wbufs = lds;
    float* abufs = lds + 4096;

    const int bx = blockIdx.x;
    const int n  = bx / TPC;
    const int l0 = (bx % TPC) * 64;

    const int tid  = threadIdx.x;
    const int rg   = tid >> 5;
    const int cg   = tid & 31;
    const int sc_  = tid >> 5;          // staging c-row 0..7
    const int sg   = tid & 31;
    const int tok  = tid & 63;          // A staging: token (tid<128)
    const int cq   = (tid >> 6) & 1;    // A staging: col quad 0..1

    float4 wreg0, wreg1;
    float4 mreg;

    auto loadW = [&](int ck) {
        const float* p = w_enc + (size_t)(ck*8 + sc_)*256 + sg*8;
        wreg0 = *reinterpret_cast<const float4*>(p);
        wreg1 = *reinterpret_cast<const float4*>(p + 4);
    };
    auto writeW = [&](int b) {
        float* d = wbufs + b*2048 + sc_*256;
        *reinterpret_cast<float4*>(d + sg*4)       = wreg0;
        *reinterpret_cast<float4*>(d + 128 + sg*4) = wreg1;
    };
    auto loadA = [&](int ck) {
        if (tid < 128)
            mreg = *reinterpret_cast<const float4*>(M + ((size_t)n*LTOT + l0 + tok)*CH + ck*8 + cq*4);
    };
    auto writeA = [&](int b) {
        if (tid < 128) {
            float* d = abufs + b*512 + tok;
            d[(cq*4+0)*64] = mreg.x;
            d[(cq*4+1)*64] = mreg.y;
            d[(cq*4+2)*64] = mreg.z;
            d[(cq*4+3)*64] = mreg.w;
        }
    };

    float acc[8][8];
    #pragma unroll
    for (int r=0;r<8;++r)
        #pragma unroll
        for (int j=0;j<8;++j) acc[r][j] = 0.f;

    loadW(0); loadA(0);
    writeW(0); writeA(0);
    __syncthreads();
    int buf = 0;
    for (int k = 0; k < 32; ++k) {
        if (k < 31) { loadW(k+1); loadA(k+1); }
        const float* wb = wbufs + buf*2048;
        const float* ab = abufs + buf*512;
        #pragma unroll 2
        for (int c = 0; c < 8; ++c) {
            float4 a0 = *reinterpret_cast<const float4*>(ab + c*64 + rg*8);
            float4 a1 = *reinterpret_cast<const float4*>(ab + c*64 + rg*8 + 4);
            float4 w0 = *reinterpret_cast<const float4*>(wb + c*256 + cg*4);
            float4 w1 = *reinterpret_cast<const float4*>(wb + c*256 + 128 + cg*4);
            float av[8] = {a0.x,a0.y,a0.z,a0.w, a1.x,a1.y,a1.z,a1.w};
            float wv[8] = {w0.x,w0.y,w0.z,w0.w, w1.x,w1.y,w1.z,w1.w};
            #pragma unroll
            for (int r=0;r<8;++r)
                #pragma unroll
                for (int j=0;j<8;++j)
                    acc[r][j] = fmaf(av[r], wv[j], acc[r][j]);
        }
        if (k < 31) { writeW(buf^1); writeA(buf^1); }
        __syncthreads();
        buf ^= 1;
    }

    // + b_enc, LayerNorm (row reduce across the 32 cg lanes)
    {
        float4 be0 = *reinterpret_cast<const float4*>(b_enc + cg*8);
        float4 be1 = *reinterpret_cast<const float4*>(b_enc + cg*8 + 4);
        float4 g0  = *reinterpret_cast<const float4*>(ln_g  + cg*8);
        float4 g1  = *reinterpret_cast<const float4*>(ln_g  + cg*8 + 4);
        float4 bb0 = *reinterpret_cast<const float4*>(ln_b  + cg*8);
        float4 bb1 = *reinterpret_cast<const float4*>(ln_b  + cg*8 + 4);
        float bev[8] = {be0.x,be0.y,be0.z,be0.w, be1.x,be1.y,be1.z,be1.w};
        float gv[8]  = {g0.x,g0.y,g0.z,g0.w, g1.x,g1.y,g1.z,g1.w};
        float bv[8]  = {bb0.x,bb0.y,bb0.z,bb0.w, bb1.x,bb1.y,bb1.z,bb1.w};
        #pragma unroll
        for (int r=0;r<8;++r) {
            float s = 0.f;
            #pragma unroll
            for (int j=0;j<8;++j) { acc[r][j] += bev[j]; s += acc[r][j]; }
            s += __shfl_xor(s,1); s += __shfl_xor(s,2); s += __shfl_xor(s,4);
            s += __shfl_xor(s,8); s += __shfl_xor(s,16);
            float mean = s * (1.f/256.f);
            float vs = 0.f;
            #pragma unroll
            for (int j=0;j<8;++j) { float d = acc[r][j]-mean; vs = fmaf(d,d,vs); }
            vs += __shfl_xor(vs,1); vs += __shfl_xor(vs,2); vs += __shfl_xor(vs,4);
            vs += __shfl_xor(vs,8); vs += __shfl_xor(vs,16);
            float rs = 1.f / sqrtf(vs*(1.f/256.f) + 1e-5f);
            #pragma unroll
            for (int j=0;j<8;++j) acc[r][j] = (acc[r][j]-mean)*rs*gv[j] + bv[j];
        }
    }

    // write out_mem (in place over M rows of this block)
    #pragma unroll
    for (int r=0;r<8;++r) {
        float* dst = M + ((size_t)n*LTOT + l0 + rg*8 + r)*CH + cg*8;
        *reinterpret_cast<float4*>(dst)   = make_float4(acc[r][0],acc[r][1],acc[r][2],acc[r][3]);
        *reinterpret_cast<float4*>(dst+4) = make_float4(acc[r][4],acc[r][5],acc[r][6],acc[r][7]);
    }

    // scores
    {
        float bcl[10];
        #pragma unroll
        for (int c=0;c<10;++c) bcl[c] = b_cls[c];
        #pragma unroll
        for (int r=0;r<8;++r) {
            float p[10];
            #pragma unroll
            for (int c=0;c<10;++c) p[c] = 0.f;
            #pragma unroll
            for (int i=0;i<8;++i) {
                const float* wc = w_cls + (cg*8+i)*10;
                float a = acc[r][i];
                #pragma unroll
                for (int c=0;c<10;c+=2) {
                    float2 w2 = *reinterpret_cast<const float2*>(wc + c);
                    p[c]   = fmaf(a, w2.x, p[c]);
                    p[c+1] = fmaf(a, w2.y, p[c+1]);
                }
            }
            #pragma unroll
            for (int c=0;c<10;++c) {
                p[c] += __shfl_xor(p[c],1); p[c] += __shfl_xor(p[c],2);
                p[c] += __shfl_xor(p[c],4); p[c] += __shfl_xor(p[c],8);
                p[c] += __shfl_xor(p[c],16);
            }
            if (cg == 0) {
                float mx = -INFINITY;
                #pragma unroll
                for (int c=0;c<10;++c) mx = fmaxf(mx, p[c] + bcl[c]);
                scores[(size_t)n*LTOT + l0 + rg*8 + r] = mx;
            }
        }
    }
}

// =====================================================================
// sort-based top-k (exact lax.top_k semantics)
// =====================================================================
typedef unsigned long long u64;

DEVI u64 pack_key(float s, unsigned idx) {
    unsigned u = __float_as_uint(s);
    u = (u & 0x80000000u) ? ~u : (u | 0x80000000u);
    return ((u64)u << 32) | (unsigned)(~idx);
}
DEVI float key_score(u64 k) {
    unsigned u = (unsigned)(k >> 32);
    u = (u & 0x80000000u) ? (u ^ 0x80000000u) : ~u;
    return __uint_as_float(u);
}
DEVI int key_idx(u64 k) { return (int)(~(unsigned)k); }

template<int N>
DEVI void bitonic_desc(u64* s, int tid) {
    for (int size = 2; size <= N; size <<= 1) {
        for (int stride = size >> 1; stride > 0; stride >>= 1) {
            __syncthreads();
            #pragma unroll 2
            for (int t = tid; t < N/2; t += 256) {
                int lo = ((t & ~(stride-1)) << 1) | (t & (stride-1));
                int hi = lo + stride;
                bool desc = ((lo & size) == 0);
                u64 a = s[lo], b = s[hi];
                if ((a < b) == desc) { s[lo] = b; s[hi] = a; }
            }
        }
    }
    __syncthreads();
}

__global__ __launch_bounds__(256)
void k_sortA(const float* __restrict__ scores, int* __restrict__ outi, float* __restrict__ outs)
{
    __shared__ u64 s[2048];
    const int b = blockIdx.x, tid = threadIdx.x;
    const int cam = b / 6, seg = b % 6;
    const float* v = scores + (size_t)cam*LTOT + seg*2016;
    for (int i = tid; i < 2048; i += 256)
        s[i] = (i < 2016) ? pack_key(v[i], seg*2016 + i) : 0ull;
    bitonic_desc<2048>(s, tid);
    if (tid < 100) {
        u64 k = s[tid];
        outi[b*100 + tid] = key_idx(k);
        outs[b*100 + tid] = key_score(k);
    }
}

__global__ __launch_bounds__(256)
void k_sortB(const int* __restrict__ ai, const float* __restrict__ as,
             int* __restrict__ ti, float* __restrict__ ts)
{
    __shared__ u64 s[1024];
    const int cam = blockIdx.x, tid = threadIdx.x;
    for (int i = tid; i < 1024; i += 256)
        s[i] = (i < 600) ? pack_key(as[cam*600 + i], (unsigned)ai[cam*600 + i]) : 0ull;
    bitonic_desc<1024>(s, tid);
    if (tid < 100) {
        u64 k = s[tid];
        ti[cam*100 + tid] = key_idx(k);
        ts[cam*100 + tid] = key_score(k);
    }
}

__global__ __launch_bounds__(256)
void k_sortC(const float* __restrict__ ts, int* __restrict__ gi)
{
    __shared__ u64 s[1024];
    const int tid = threadIdx.x;
    for (int i = tid; i < 1024; i += 256)
        s[i] = (i < 600) ? pack_key(ts[i], (unsigned)i) : 0ull;
    bitonic_desc<1024>(s, tid);
    if (tid < 200) gi[tid] = key_idx(s[tid]);
}

// =====================================================================
// K3: per selected query: bbox MLP + depth net + center2lidar
// =====================================================================
__global__ __launch_bounds__(256)
void k_query(const float* __restrict__ out_mem, const int* __restrict__ topk_ind,
             const float* __restrict__ intr, const float* __restrict__ ext_inv,
             const float* __restrict__ w_bb1, const float* __restrict__ b_bb1,
             const float* __restrict__ w_bb2, const float* __restrict__ b_bb2,
             const float* __restrict__ w_bb3, const float* __restrict__ b_bb3,
             const float* __restrict__ depth_bins,
             const float* __restrict__ w_d1, const float* __restrict__ b_d1,
             const float* __restrict__ w_d2, const float* __restrict__ b_d2,
             float* __restrict__ dyn_all)
{
    __shared__ float sq[272];
    __shared__ float sh[256];
    __shared__ float sh2[256];
    __shared__ float sbb[2];
    const int nk = blockIdx.x;
    const int n = nk / 100;
    const int tid = threadIdx.x;
    const int l = topk_ind[nk];
    sq[tid] = out_mem[((size_t)n*LTOT + l)*CH + tid];
    if (tid < 16) sq[256+tid] = intr[n*16+tid] * 0.01f;
    __syncthreads();
    float s1 = b_bb1[tid];
    for (int c=0;c<256;++c) s1 = fmaf(sq[c], w_bb1[c*256+tid], s1);
    sh[tid] = fmaxf(s1, 0.f);
    __syncthreads();
    float s2 = b_bb2[tid];
    for (int c=0;c<256;++c) s2 = fmaf(sh[c], w_bb2[c*256+tid], s2);
    sh2[tid] = fmaxf(s2, 0.f);
    __syncthreads();
    {
        int j = tid >> 6, c0 = tid & 63;
        if (j < 2) {
            float p = 0.f;
            #pragma unroll
            for (int t=0;t<4;++t) { int c = c0 + t*64; p = fmaf(sh2[c], w_bb3[c*4+j], p); }
            #pragma unroll
            for (int m=1;m<64;m<<=1) p += __shfl_xor(p, m);
            if (c0 == 0) sbb[j] = p + b_bb3[j] + anchor_comp(l, j);
        }
    }
    float t1 = b_d1[tid];
    for (int c=0;c<272;++c) t1 = fmaf(sq[c], w_d1[c*256+tid], t1);
    sh[tid] = fmaxf(t1, 0.f);
    __syncthreads();
    if (tid < 64) {
        float dl = b_d2[tid];
        for (int c=0;c<256;++c) dl = fmaf(sh[c], w_d2[c*64+tid], dl);
        if (isnan(dl)) dl = 0.f;
        if (isinf(dl)) dl = (dl > 0.f) ? 1e4f : -1e4f;
        float mx = dl;
        #pragma unroll
        for (int m=1;m<64;m<<=1) mx = fmaxf(mx, __shfl_xor(mx, m));
        float e = expf(dl - mx);
        float sum = e;
        #pragma unroll
        for (int m=1;m<64;m<<=1) sum += __shfl_xor(sum, m);
        float dp = e / sum;
        float fx = fmaxf(intr[n*16+0], 1e-6f);
        float fy = fmaxf(intr[n*16+5], 1e-6f);
        float cx = intr[n*16+2], cy = intr[n*16+6];
        float sx = 1.f/(1.f+expf(-sbb[0]));
        float sy = 1.f/(1.f+expf(-sbb[1]));
        float c2dx = sx * 1024.f, c2dy = sy * 576.f;
        float dep = depth_bins[tid];
        float X = (c2dx - cx)/fx*dep;
        float Y = (c2dy - cy)/fy*dep;
        const float* EI = ext_inv + n*16;
        float c0v = EI[0]*X + EI[1]*Y + EI[2]*dep + EI[3];
        float c1v = EI[4]*X + EI[5]*Y + EI[6]*dep + EI[7];
        float c2v = EI[8]*X + EI[9]*Y + EI[10]*dep + EI[11];
        float4 o = make_float4(c0v, c1v, c2v, dp);
        *reinterpret_cast<float4*>(dyn_all + ((size_t)nk*64 + tid)*4) = o;
    }
}

// =====================================================================
// K5: gather final 200 queries
// =====================================================================
__global__ __launch_bounds__(256)
void k_gather(const float* __restrict__ dyn_all, const int* __restrict__ gidx,
              const int* __restrict__ topk_ind, const float* __restrict__ out_mem,
              float* __restrict__ out)
{
    int g = blockIdx.x, tid = threadIdx.x;
    int src = gidx[g];
    out[O_DQ + (size_t)g*256 + tid] = dyn_all[(size_t)src*256 + tid];
    int n = src/100; int l = topk_ind[src];
    out[O_QF + (size_t)g*256 + tid] = out_mem[((size_t)n*LTOT + l)*CH + tid];
}

// =====================================================================
// K6a: MLN gamma/beta — one block per camera (was 6 cams serial in 1 block)
// =====================================================================
__global__ __launch_bounds__(256)
void k_mln(const float* __restrict__ intr, const float* __restrict__ ext,
           const float* __restrict__ w_m1, const float* __restrict__ b_m1,
           const float* __restrict__ w_mg, const float* __restrict__ b_mg,
           const float* __restrict__ w_mb, const float* __restrict__ b_mb,
           float* __restrict__ gamma, float* __restrict__ beta)
{
    __shared__ float hm[256];
    const int n = blockIdx.x;
    const int tid = threadIdx.x;
    float m[14];
    m[0] = intr[n*16+0] / 1000.0f;
    m[1] = intr[n*16+5] / 1000.0f;
    #pragma unroll
    for (int j=0;j<12;++j) m[2+j] = ext[n*16+j];
    float h = b_m1[tid];
    #pragma unroll
    for (int k=0;k<14;++k) h = fmaf(m[k], w_m1[k*256+tid], h);
    hm[tid] = fmaxf(h, 0.f);
    __syncthreads();
    float g = b_mg[tid], bt = b_mb[tid];
    for (int c=0;c<256;++c) {
        float hv = hm[c];
        g  = fmaf(hv, w_mg[c*256+tid], g);
        bt = fmaf(hv, w_mb[c*256+tid], bt);
    }
    gamma[n*256+tid] = g;
    beta[n*256+tid]  = bt;
}

// =====================================================================
// K6b: feat_flatten = transpose(feat) * gamma + beta  (64x64 LDS tiles)
// =====================================================================
__global__ __launch_bounds__(256)
void k_flatten(const float* __restrict__ f0, const float* __restrict__ f1,
               const float* __restrict__ gamma, const float* __restrict__ beta,
               float* __restrict__ out)
{
    __shared__ float t[64][65];
    int b = blockIdx.x;
    int lt = b % 180, ct = (b/180) & 3, n = b / 720;
    int l0 = lt*64, c0 = ct*64;
    const float* f; int HW, lb;
    if (l0 < 9216) { f=f0; HW=9216; lb=l0; } else { f=f1; HW=2304; lb=l0-9216; }
    int tid = threadIdx.x;
    int cl = tid >> 4, lw = (tid & 15)*4;
    #pragma unroll
    for (int rep=0;rep<4;++rep) {
        int cc = cl + rep*16;
        float4 v = *reinterpret_cast<const float4*>(f + ((size_t)n*CH + c0+cc)*HW + lb + lw);
        t[cc][lw+0]=v.x; t[cc][lw+1]=v.y; t[cc][lw+2]=v.z; t[cc][lw+3]=v.w;
    }
    __syncthreads();
    int ll = tid >> 4, cw = (tid & 15)*4;
    float4 gv = *reinterpret_cast<const float4*>(gamma + n*256 + c0 + cw);
    float4 bv = *reinterpret_cast<const float4*>(beta  + n*256 + c0 + cw);
    #pragma unroll
    for (int rep=0;rep<4;++rep) {
        int l = ll + rep*16;
        float4 o;
        o.x = fmaf(t[cw+0][l], gv.x, bv.x);
        o.y = fmaf(t[cw+1][l], gv.y, bv.y);
        o.z = fmaf(t[cw+2][l], gv.z, bv.z);
        o.w = fmaf(t[cw+3][l], gv.w, bv.w);
        *reinterpret_cast<float4*>(out + ((size_t)n*LIMG + l0 + l)*CH + c0 + cw) = o;
    }
}

// =====================================================================
// K7: spatial_flatten consts + lidar2img
// =====================================================================
__global__ void k_small(const float* __restrict__ intr, const float* __restrict__ ext,
                        float* __restrict__ out)
{
    int tid = threadIdx.x;
    if (tid < 4) {
        const float sp[4] = {72.f, 128.f, 36.f, 64.f};
        out[O_SP + tid] = sp[tid];
    }
    if (tid < 96) {
        int n = tid >> 4, i = (tid >> 2) & 3, k = tid & 3;
        float s = 0.f;
        #pragma unroll
        for (int j=0;j<4;++j) s = fmaf(intr[n*16 + i*4 + j], ext[n*16 + j*4 + k], s);
        out[O_L2I + tid] = s;
    }
}

// =====================================================================
extern "C" void kernel_launch(void* const* d_in, const int* in_sizes, int n_in,
                              void* d_out, int out_size, void* d_ws, size_t ws_size,
                              hipStream_t stream) {
    const float* f0      = (const float*)d_in[0];
    const float* f1      = (const float*)d_in[1];
    const float* f2      = (const float*)d_in[2];
    const float* intr    = (const float*)d_in[3];
    const float* ext     = (const float*)d_in[4];
    const float* ext_inv = (const float*)d_in[5];
    const float* wp0     = (const float*)d_in[6];
    const float* wp1     = (const float*)d_in[7];
    const float* wp2     = (const float*)d_in[8];
    const float* w_enc   = (const float*)d_in[9];
    const float* b_enc   = (const float*)d_in[10];
    const float* ln_g    = (const float*)d_in[11];
    const float* ln_b    = (const float*)d_in[12];
    const float* w_cls   = (const float*)d_in[13];
    const float* b_cls   = (const float*)d_in[14];
    const float* w_bb1   = (const float*)d_in[15];
    const float* b_bb1   = (const float*)d_in[16];
    const float* w_bb2   = (const float*)d_in[17];
    const float* b_bb2   = (const float*)d_in[18];
    const float* w_bb3   = (const float*)d_in[19];
    const float* b_bb3   = (const float*)d_in[20];
    const float* dbins   = (const float*)d_in[21];
    const float* w_d1    = (const float*)d_in[22];
    const float* b_d1    = (const float*)d_in[23];
    const float* w_d2    = (const float*)d_in[24];
    const float* b_d2    = (const float*)d_in[25];
    const float* w_m1    = (const float*)d_in[26];
    const float* b_m1    = (const float*)d_in[27];
    const float* w_mg    = (const float*)d_in[28];
    const float* b_mg    = (const float*)d_in[29];
    const float* w_mb    = (const float*)d_in[30];
    const float* b_mb    = (const float*)d_in[31];

    float* ws  = (float*)d_ws;
    float* out = (float*)d_out;
    float* om  = ws + WS_OM;
    float* sc  = ws + WS_SC;
    int*   ti  = (int*)(ws + WS_TI);
    float* ts  = ws + WS_TS;
    float* da  = ws + WS_DA;
    int*   gi  = (int*)(ws + WS_GI);
    float* ga  = ws + WS_GA;
    float* be  = ws + WS_BE;
    int*   ai  = (int*)(ws + WS_AI);
    float* as  = ws + WS_AS;

    k_proj<<<CAMS*TPC, 256, 0, stream>>>(f0, f1, f2, wp0, wp1, wp2, om);
    k_enc<<<CAMS*TPC, 256, 0, stream>>>(om, w_enc, b_enc, ln_g, ln_b, w_cls, b_cls, sc);
    k_sortA<<<36, 256, 0, stream>>>(sc, ai, as);
    k_sortB<<<6, 256, 0, stream>>>(ai, as, ti, ts);
    k_query<<<600, 256, 0, stream>>>(om, ti, intr, ext_inv,
                                     w_bb1, b_bb1, w_bb2, b_bb2, w_bb3, b_bb3,
                                     dbins, w_d1, b_d1, w_d2, b_d2, da);
    k_sortC<<<1, 256, 0, stream>>>(ts, gi);
    k_gather<<<200, 256, 0, stream>>>(da, gi, ti, om, out);
    k_mln<<<CAMS, 256, 0, stream>>>(intr, ext, w_m1, b_m1, w_mg, b_mg, w_mb, b_mb, ga, be);
    k_flatten<<<6*4*180, 256, 0, stream>>>(f0, f1, ga, be, out);
    k_small<<<1, 128, 0, stream>>>(intr, ext, out);
}